// Round 2
// baseline (574.657 us; speedup 1.0000x reference)
//
#include <hip/hip_runtime.h>

// TT embedding bag, load-balanced formulation.
// idx = pair*50 + d2, pair < 2500, d2 < 50.
// t_table[pair][kk*32+s] = sum_r core0[d0][x*32+r]*core1[d1][r*128+y*32+s], kk=x*4+y
// core2T[d2][z*32+r]     = core2[d2][r*8+z]
// emb[kk*8+z] = dot32(t_table[pair][kk*32..], core2T[d2][z*32..])

#define PAIRS 2500
#define TROW 512
#define NBAGS_DEFAULT 4096
#define CHT 32   // TT positions per block
#define CHC 64   // cached positions per block

__global__ __launch_bounds__(256) void build_tables_kernel(
    const float* __restrict__ core0, const float* __restrict__ core1,
    const float* __restrict__ core2, float* __restrict__ t_table,
    float* __restrict__ core2T) {
  const int bid = blockIdx.x;
  const int tid = threadIdx.x;
  if (bid < PAIRS) {
    __shared__ float c0[128];
    __shared__ float c1[4096];
    const int d0 = bid / 50, d1 = bid - d0 * 50;
    const float4* src1 = reinterpret_cast<const float4*>(core1 + (size_t)d1 * 4096);
    float4* dst1 = reinterpret_cast<float4*>(c1);
    for (int i = tid; i < 1024; i += 256) dst1[i] = src1[i];
    if (tid < 32) {
      reinterpret_cast<float4*>(c0)[tid] =
          reinterpret_cast<const float4*>(core0 + (size_t)d0 * 128)[tid];
    }
    __syncthreads();
#pragma unroll
    for (int q = 0; q < 2; ++q) {
      const int o = tid + q * 256;
      const int kk = o >> 5, s = o & 31;
      const int x = kk >> 2, y = kk & 3;
      float acc = 0.f;
#pragma unroll
      for (int r = 0; r < 32; ++r)
        acc += c0[x * 32 + r] * c1[r * 128 + y * 32 + s];
      t_table[(size_t)bid * TROW + o] = acc;
    }
  } else {
    // transpose one core2 row: bid-PAIRS = d2
    const int d2 = bid - PAIRS;
    if (tid < 256) {
      const int z = tid >> 5, r = tid & 31;
      core2T[(size_t)d2 * 256 + tid] = core2[(size_t)d2 * 256 + r * 8 + z];
    }
  }
}

__device__ __forceinline__ int bag_search(const int* __restrict__ offs,
                                          int nbags, int p) {
  int lo = 0, hi = nbags;  // offs[0]=0 <= p < offs[nbags]
  while (hi - lo > 1) {
    int m = (lo + hi) >> 1;
    if (offs[m] <= p) lo = m; else hi = m;
  }
  return lo;
}

__global__ __launch_bounds__(128) void bag_main_kernel(
    const int* __restrict__ indices, const int* __restrict__ offsets,
    const int* __restrict__ cached_indices, const int* __restrict__ cached_offsets,
    const float* __restrict__ cache_table, const float* __restrict__ t_table,
    const float* __restrict__ core2T, float* __restrict__ out,
    int n, int nbags, int ntt_blocks) {
  const int tid = threadIdx.x;
  const int bid = blockIdx.x;

  if (bid < ntt_blocks) {
    // ---------------- TT part ----------------
    __shared__ int spair[CHT], sd2[CHT], sbag[CHT];
    const int base = bid * CHT;
    const int count = min(CHT, n - base);
    if (tid < count) {
      const int p = base + tid;
      const int idx = indices[p];
      const int pr = idx / 50;
      spair[tid] = pr;
      sd2[tid] = idx - pr * 50;
      sbag[tid] = bag_search(offsets, nbags, p);
    }
    __syncthreads();

    const int kk = tid >> 3, z = tid & 7;
    float acc = 0.f;
    for (int i = 0; i < count; ++i) {
      const float4* __restrict__ tr =
          reinterpret_cast<const float4*>(t_table + (size_t)spair[i] * TROW + kk * 32);
      const float4* __restrict__ gr =
          reinterpret_cast<const float4*>(core2T + (size_t)sd2[i] * 256 + z * 32);
      float s = 0.f;
#pragma unroll
      for (int r = 0; r < 8; ++r) {
        const float4 a = tr[r];
        const float4 b = gr[r];
        s += a.x * b.x + a.y * b.y + a.z * b.z + a.w * b.w;
      }
      acc += s;
      const int bg = sbag[i];
      if (i == count - 1 || sbag[i + 1] != bg) {
        atomicAdd(out + (size_t)bg * 128 + tid, acc);
        acc = 0.f;
      }
    }
  } else {
    // ---------------- cached part ----------------
    __shared__ int sci[CHC], sbg[CHC];
    const int cbid = bid - ntt_blocks;
    const int base = cbid * CHC;
    const int count = min(CHC, n - base);
    if (tid < count) {
      const int p = base + tid;
      sci[tid] = cached_indices[p];
      sbg[tid] = bag_search(cached_offsets, nbags, p);
    }
    __syncthreads();

    float acc = 0.f;
    for (int i = 0; i < count; ++i) {
      acc += cache_table[(size_t)sci[i] * 128 + tid];
      const int bg = sbg[i];
      if (i == count - 1 || sbg[i + 1] != bg) {
        atomicAdd(out + (size_t)bg * 128 + tid, acc);
        acc = 0.f;
      }
    }
  }
}

extern "C" void kernel_launch(void* const* d_in, const int* in_sizes, int n_in,
                              void* d_out, int out_size, void* d_ws, size_t ws_size,
                              hipStream_t stream) {
  const int* indices        = (const int*)d_in[0];
  const int* offsets        = (const int*)d_in[1];
  const int* cached_indices = (const int*)d_in[2];
  const int* cached_offsets = (const int*)d_in[3];
  const float* core0        = (const float*)d_in[4];
  const float* core1        = (const float*)d_in[5];
  const float* core2        = (const float*)d_in[6];
  const float* cache_table  = (const float*)d_in[7];
  float* out = (float*)d_out;

  const int n = in_sizes[0];             // 204800
  const int nbags = in_sizes[1] - 1;     // 4096

  float* t_table = (float*)d_ws;                       // 5,120,000 B
  float* core2T  = (float*)((char*)d_ws + (size_t)PAIRS * TROW * 4);  // +51,200 B

  // zero the output (it is poisoned before every timed call)
  hipMemsetAsync(out, 0, (size_t)out_size * sizeof(float), stream);

  build_tables_kernel<<<PAIRS + 50, 256, 0, stream>>>(core0, core1, core2,
                                                      t_table, core2T);

  const int ntt = (n + CHT - 1) / CHT;   // 6400
  const int nc  = (n + CHC - 1) / CHC;   // 3200
  bag_main_kernel<<<ntt + nc, 128, 0, stream>>>(
      indices, offsets, cached_indices, cached_offsets, cache_table, t_table,
      core2T, out, n, nbags, ntt);
}